// Round 9
// baseline (187.470 us; speedup 1.0000x reference)
//
#include <hip/hip_runtime.h>

typedef unsigned short u16;
typedef __bf16 bf16x8 __attribute__((ext_vector_type(8)));
typedef float f32x4 __attribute__((ext_vector_type(4)));
typedef float f32x16 __attribute__((ext_vector_type(16)));
typedef unsigned int u32x4 __attribute__((ext_vector_type(4)));
typedef int i32x2 __attribute__((ext_vector_type(2)));

// B=2, S=2048, E=1024, HID=1024, HEADS=16 -> M=4096 rows, 3N=3072, 32 (h,b) pairs
static constexpr float SCALE2 = 0.022097086912079608f * 1.4426950408889634f;  // qk scale * log2(e)

__device__ __forceinline__ u16 f2b(float f) {
  union { float f; unsigned int i; } v; v.f = f;
  unsigned int r = v.i + 0x7fffu + ((v.i >> 16) & 1u);  // RNE
  return (u16)(r >> 16);
}
// pack two f32 -> two bf16 in one u32 (HW cvt_pk if available)
__device__ __forceinline__ unsigned int pk2(float a, float b) {
#if __has_builtin(__builtin_amdgcn_cvt_pk_bf16_f32)
  auto v = __builtin_amdgcn_cvt_pk_bf16_f32(a, b);
  unsigned int u;
  __builtin_memcpy(&u, &v, 4);
  return u;
#else
  union { float f; unsigned int i; } x, y; x.f = a; y.f = b;
  return ((x.i + 0x8000u) >> 16) | ((y.i + 0x8000u) & 0xffff0000u);
#endif
}
// permlane32_swap: exchange lanes 0-31 of one reg with lanes 32-63 of another.
// returns {d, s}: d = [a_lo | b_lo], s = [a_hi | b_hi]  (lo = lanes 0-31 view)
__device__ __forceinline__ i32x2 plswap(unsigned int a, unsigned int b) {
#if __has_builtin(__builtin_amdgcn_permlane32_swap)
  return __builtin_amdgcn_permlane32_swap((int)a, (int)b, false, false);
#else
  int d = (int)a, s = (int)b;
  asm volatile("v_permlane32_swap_b32 %0, %1" : "+v"(d), "+v"(s));
  i32x2 r; r[0] = d; r[1] = s; return r;
#endif
}
__device__ __forceinline__ void async16(const u16* g, u16* l) {
  __builtin_amdgcn_global_load_lds((const __attribute__((address_space(1))) void*)g,
                                   (__attribute__((address_space(3))) void*)l,
                                   16, 0, 0);
}

// ---- fused pre-pass (R8): LN wave-per-row (blocks 0..1023, 4 rows/block,
// no LDS, no barriers) + W1/W2 transpose+cast (1024..2047) ----
__global__ __launch_bounds__(256) void pre_kernel(const float* __restrict__ x,
                                                  const float* __restrict__ lg,
                                                  const float* __restrict__ lb,
                                                  u16* __restrict__ xn,
                                                  const float* __restrict__ W1,
                                                  u16* __restrict__ W1T,
                                                  const float* __restrict__ W2,
                                                  u16* __restrict__ W2T) {
  __shared__ __align__(16) u16 smem[64 * 72];
  const int bx = blockIdx.x;
  const int t = threadIdx.x;
  if (bx < 1024) {
    // -------- LayerNorm: wave w owns row bx*4 + w; pure shfl reduce --------
    const int w = t >> 6, lane = t & 63;
    const int row = bx * 4 + w;
    const float* xr = x + (size_t)row * 1024;
    float4 v[4];
    float s = 0.f, ss = 0.f;
#pragma unroll
    for (int k = 0; k < 4; k++) {
      v[k] = *(const float4*)(xr + k * 256 + lane * 4);
      s += v[k].x + v[k].y + v[k].z + v[k].w;
      ss += v[k].x * v[k].x + v[k].y * v[k].y + v[k].z * v[k].z + v[k].w * v[k].w;
    }
#pragma unroll
    for (int off = 32; off >= 1; off >>= 1) {
      s += __shfl_xor(s, off, 64);
      ss += __shfl_xor(ss, off, 64);
    }
    const float mu = s * (1.0f / 1024.0f);
    const float var = ss * (1.0f / 1024.0f) - mu * mu;
    const float inv = rsqrtf(var + 1e-5f);
#pragma unroll
    for (int k = 0; k < 4; k++) {
      float4 gg = *(const float4*)(lg + k * 256 + lane * 4);
      float4 bb = *(const float4*)(lb + k * 256 + lane * 4);
      ushort4 o;
      o.x = f2b((v[k].x - mu) * inv * gg.x + bb.x);
      o.y = f2b((v[k].y - mu) * inv * gg.y + bb.y);
      o.z = f2b((v[k].z - mu) * inv * gg.z + bb.z);
      o.w = f2b((v[k].w - mu) * inv * gg.w + bb.w);
      *(ushort4*)(xn + (size_t)row * 1024 + k * 256 + lane * 4) = o;
    }
    return;
  }
  // -------- weight transpose tile --------
  const float* in;
  u16* out;
  int C, c0, r0;
  if (bx < 1024 + 768) {
    const int idx = bx - 1024;
    C = 3072; in = W1; out = W1T;
    c0 = (idx % 48) * 64; r0 = (idx / 48) * 64;
  } else {
    const int idx = bx - 1792;
    C = 1024; in = W2; out = W2T;
    c0 = (idx % 16) * 64; r0 = (idx / 16) * 64;
  }
  const int row = t >> 2, cseg = t & 3;
  for (int it = 0; it < 4; it++) {
    float4 v = *(const float4*)&in[(size_t)(r0 + row) * C + c0 + it * 16 + cseg * 4];
    ushort4 o;
    o.x = f2b(v.x); o.y = f2b(v.y); o.z = f2b(v.z); o.w = f2b(v.w);
    *(ushort4*)&smem[row * 72 + it * 16 + cseg * 4] = o;
  }
  __syncthreads();
  const int orow = t >> 2, ch = t & 3;
  u16 vals[16];
  for (int j = 0; j < 16; j++) vals[j] = smem[(ch * 16 + j) * 72 + orow];
  u16* dp = out + (size_t)(c0 + orow) * 1024 + r0 + ch * 16;
  *(uint4*)&dp[0] = *(uint4*)&vals[0];
  *(uint4*)&dp[8] = *(uint4*)&vals[8];
}

// ------- GEMM (B^T input): C[M][N] = A[M][K] * Bt[N][K]^T + bias -------
// R7: BK 32->64 (32 MFMAs per barrier-pair, half the barrier drains) +
// bijective XCD swizzle (1D grid, nwg%8==0).  LDS layout [rows][64] with
// chunk^(row&7) XOR swizzle (16-B chunks), consistent between staging
// (pre-swizzled global source) and fragment reads -> <=2-way conflicts.
// MT x 128 block tile, 4 waves (2x2), 16x16x32 MFMA.
// MODE 0: C = float* row-major.
// MODE 1 (MT=128 only): coalesced bf16 stores into Qc/Kc/Vtmp [g][2048][64];
//   Q values pre-scaled by SCALE2 (folded attention scale).
template <int MODE, int MT>
__global__ __launch_bounds__(256) void gemm_bt(const u16* __restrict__ A,
                                               const u16* __restrict__ Bt,
                                               const float* __restrict__ bias,
                                               float* __restrict__ C,
                                               int M, int N, int K, int nbx,
                                               u16* __restrict__ Qc,
                                               u16* __restrict__ Kc,
                                               u16* __restrict__ Vtmp) {
  __shared__ __align__(16) u16 SMEM[(MT + 128) * 64];
  u16* As = SMEM;            // [MT][64]
  u16* Bs = SMEM + MT * 64;  // [128][64]
  // XCD-aware bijective remap: consecutive blockIdx round-robin XCDs ->
  // give each XCD a contiguous run of tiles (A-panel L2 reuse).
  const int nwg = gridDim.x, cpx = nwg >> 3;
  const int l0 = blockIdx.x;
  const int l2 = (l0 & 7) * cpx + (l0 >> 3);
  const int bx = l2 % nbx, by = l2 / nbx;
  const int m0 = by * MT, n0 = bx * 128;
  const int t = threadIdx.x, w = t >> 6, lane = t & 63;
  const int q = lane >> 4, l16 = lane & 15;
  const int wm = (w >> 1) * (MT / 2), wn = (w & 1) * 64;
  constexpr int NI = MT / 32;

  // staging: each async16 covers 8 rows x 64 cols; lane (l>>3)=row, (l&7)=chunk.
  // LDS[r][c] = G[r][c ^ (r&7)]  (chunks of 8 u16)
  const int gchunk = (lane & 7) ^ ((lane >> 3) & 7);
  const u16* ap = A + (size_t)(m0 + w * 8 + (lane >> 3)) * K + gchunk * 8;
  const u16* bp = Bt + (size_t)(n0 + w * 8 + (lane >> 3)) * K + gchunk * 8;
  u16* lA = &As[w * 512];
  u16* lB = &Bs[w * 512];

  f32x4 acc[NI][4];
  const f32x4 zero = {0.f, 0.f, 0.f, 0.f};
  for (int i = 0; i < NI; i++)
    for (int j = 0; j < 4; j++) acc[i][j] = zero;

  for (int k0 = 0; k0 < K; k0 += 64) {
    for (int i = 0; i < MT / 32; i++)
      async16(ap + (size_t)(i * 32) * K, lA + i * 2048);
    for (int i = 0; i < 4; i++)
      async16(bp + (size_t)(i * 32) * K, lB + i * 2048);
    ap += 64; bp += 64;
    __syncthreads();
    for (int kk = 0; kk < 2; kk++) {
      bf16x8 af[NI], bfr[4];
      for (int i = 0; i < NI; i++) {
        const int r = wm + i * 16 + l16;
        af[i] = *(const bf16x8*)&As[r * 64 + (((kk * 4 + q) ^ (r & 7)) * 8)];
      }
      for (int j = 0; j < 4; j++) {
        const int r = wn + j * 16 + l16;
        bfr[j] = *(const bf16x8*)&Bs[r * 64 + (((kk * 4 + q) ^ (r & 7)) * 8)];
      }
      for (int i = 0; i < NI; i++)
        for (int j = 0; j < 4; j++)
          acc[i][j] = __builtin_amdgcn_mfma_f32_16x16x32_bf16(af[i], bfr[j], acc[i][j], 0, 0, 0);
    }
    __syncthreads();
  }

  if constexpr (MODE == 0) {
    for (int j = 0; j < 4; j++) {
      const int col = n0 + wn + j * 16 + l16;
      const float bv = bias[col];
      for (int i = 0; i < NI; i++) {
        const int rbase = m0 + wm + i * 16 + q * 4;
        for (int r = 0; r < 4; r++)
          C[(size_t)(rbase + r) * N + col] = acc[i][j][r] + bv;
      }
    }
  } else {
    // wave's 64-col segment: one type, fixed tcol.  seg = 64k -> typ = k%3, tcol = k/3.
    const int seg = n0 + wn;
    const int k64 = seg >> 6;
    const int tcol = k64 / 3;
    const int typ = k64 - tcol * 3;  // 0=Q,1=K,2=V
    u16* dst = (typ == 0) ? Qc : (typ == 1) ? Kc : Vtmp;
    const float qs = (typ == 0) ? SCALE2 : 1.0f;  // fold attention scale into Q
    const int gidx = m0 >> 7;
    u16* tw = &SMEM[w * 1280];  // [64 cols][20] u16, wave-private
    float bv[4];
    for (int j = 0; j < 4; j++) bv[j] = bias[seg + j * 16 + l16];
    __syncthreads();  // all waves done with As/Bs MFMA reads
    for (int i = 0; i < 4; i++) {
      for (int j = 0; j < 4; j++) {
        ushort4 pk;
        pk.x = f2b((acc[i][j][0] + bv[j]) * qs);
        pk.y = f2b((acc[i][j][1] + bv[j]) * qs);
        pk.z = f2b((acc[i][j][2] + bv[j]) * qs);
        pk.w = f2b((acc[i][j][3] + bv[j]) * qs);
        *(ushort4*)&tw[(j * 16 + l16) * 20 + q * 4] = pk;  // col-major, pad 20
      }
      const int r2 = lane >> 2;
      const int quarter = lane & 3;
      u16 vals[16];
      for (int c = 0; c < 16; c++)
        vals[c] = tw[(quarter * 16 + c) * 20 + r2];
      const int lr = wm + i * 16 + r2;
      const int s = (lr << 4) + tcol;
      u16* dp = dst + ((size_t)gidx * 2048 + s) * 64 + quarter * 16;
      *(uint4*)&dp[0] = *(uint4*)&vals[0];
      *(uint4*)&dp[8] = *(uint4*)&vals[8];
    }
  }
}

// ------- vtrans: Vtmp[g][2048][64] -> Vt[g][64][2048], 64x64 LDS tiles -------
__global__ __launch_bounds__(256) void vtrans(const u16* __restrict__ Vtmp,
                                              u16* __restrict__ Vt) {
  __shared__ __align__(16) u16 tile[64 * 64];  // XOR-swizzled chunks
  const int g = blockIdx.y, s0 = blockIdx.x * 64;
  const int t = threadIdx.x;
  const int row = t >> 3, ch = t & 7;
  for (int p = 0; p < 2; p++) {
    const int r = p * 32 + row;
    uint4 v = *(const uint4*)&Vtmp[((size_t)g * 2048 + s0 + r) * 64 + ch * 8];
    *(uint4*)&tile[r * 64 + ((ch ^ (r & 7)) * 8)] = v;
  }
  __syncthreads();
  const int d = t >> 2, scn = t & 3;
  u16 vals[16];
  for (int j2 = 0; j2 < 16; j2++) {
    const int s = scn * 16 + j2;
    vals[j2] = tile[s * 64 + (((d >> 3) ^ (s & 7)) * 8) + (d & 7)];
  }
  u16* dp = Vt + ((size_t)g * 64 + d) * 2048 + s0 + scn * 16;
  *(uint4*)&dp[0] = *(uint4*)&vals[0];
  *(uint4*)&dp[8] = *(uint4*)&vals[8];
}

// ------- flash attention: 1 block per (g, q-tile 128), 8 waves -------
// Verbatim R3 structure (best measured: attn 48.6-50.8 us).
// 8 waves = 2 kv-halves x 4 q-strips(32); 32x32 MFMA; in-register
// P redistribution (cvt_pk + permlane32_swap); no Ps LDS; 64-kv sub-tiles,
// double-buffered K/V via global_load_lds.
// Swizzles (c = 16-B chunk): Ks[s'][c]=K[s'][c^(s'&7)], Vs[d][c]=V^T[d][c^(d&7)].
__global__ __launch_bounds__(512) void attn_kernel(const u16* __restrict__ Qc,
                                                   const u16* __restrict__ Kc,
                                                   const u16* __restrict__ Vt,
                                                   u16* __restrict__ Oc) {
  __shared__ __align__(16) u16 LDS[25600];  // 50 KB: K dbuf 16K | V dbuf 16K | epilogue reuse
  u16* K0 = LDS;           // [64][64] buf 0
  u16* K1 = LDS + 4096;    // buf 1
  u16* V0 = LDS + 8192;    // V^T slice [64][64] buf 0
  u16* V1 = LDS + 12288;   // buf 1
  const int g = blockIdx.y;
  const int q0 = blockIdx.x * 128;
  const int t = threadIdx.x, w = t >> 6, lane = t & 63;
  const int l31 = lane & 31, h = lane >> 5;
  const int qs = w & 3;           // q-strip (32 rows)
  const int kvb = (w >> 2) * 32;  // kv half base

  const u16* Qg = Qc + (size_t)g * 2048 * 64;
  const u16* Kg = Kc + (size_t)g * 2048 * 64;
  const u16* Vg = Vt + (size_t)g * 64 * 2048;

  // Q B-frags (pre-scaled by SCALE2): lane: col q=l31, k(d) = s*16 + h*8 + j
  bf16x8 aq[4];
#pragma unroll
  for (int s = 0; s < 4; s++)
    aq[s] = *(const bf16x8*)&Qg[(size_t)(q0 + qs * 32 + l31) * 64 + s * 16 + h * 8];

  f32x16 accO[2];  // O^T partial (this wave's kv half): d = tt*32+(r&3)+8*(r>>2)+4h, q=l31
#pragma unroll
  for (int tt = 0; tt < 2; tt++)
#pragma unroll
    for (int r = 0; r < 16; r++) accO[tt][r] = 0.f;
  float psv = 0.f;  // partial l-sum (this lane's 16 kv rows, q=l31)

  // staging: wave w covers rows w*8..w*8+7 of each 64-row tile (1 K + 1 V load)
  const int ch = (lane & 7) ^ ((lane >> 3) & 7);
  const u16* kp = Kg + (size_t)(w * 8 + (lane >> 3)) * 64 + ch * 8;
  const u16* vp = Vg + (size_t)(w * 8 + (lane >> 3)) * 2048 + ch * 8;
  u16* lK0 = K0 + w * 512;
  u16* lK1 = K1 + w * 512;
  u16* lV0 = V0 + w * 512;
  u16* lV1 = V1 + w * 512;

  const int rsw = l31 & 7;  // row-based chunk swizzle for A-frag reads

  // prologue: stage tile 0 into buf 0
  async16(kp, lK0);
  async16(vp, lV0);
  __syncthreads();

  for (int it = 0; it < 32; it++) {
    const int cur = it & 1;
    const u16* Kcur = cur ? K1 : K0;
    const u16* Vcur = cur ? V1 : V0;
    // prefetch next tile into the other buffer (overlaps with compute below)
    if (it < 31) {
      const int kt0 = (it + 1) * 64;
      async16(kp + (size_t)kt0 * 64, cur ? lK0 : lK1);
      async16(vp + kt0, cur ? lV0 : lV1);
    }

    // S^T[32kv][32q] = K Q^T  (A: row kv=kvb+l31, k = s*16+h*8+j)
    f32x16 sa;
#pragma unroll
    for (int r = 0; r < 16; r++) sa[r] = 0.f;
    __builtin_amdgcn_s_setprio(1);
#pragma unroll
    for (int s = 0; s < 4; s++) {
      bf16x8 ak = *(const bf16x8*)&Kcur[(kvb + l31) * 64 + (((s * 2 + h) ^ rsw) * 8)];
      sa = __builtin_amdgcn_mfma_f32_32x32x16_bf16(ak, aq[s], sa, 0, 0, 0);
    }
    __builtin_amdgcn_s_setprio(0);

    // softmax: exp2, l-sum partial, pack to bf16 pairs, permlane32 redistribution
    float e[16];
#pragma unroll
    for (int r = 0; r < 16; r++) e[r] = __builtin_amdgcn_exp2f(sa[r]);
    psv += (((e[0] + e[1]) + (e[2] + e[3])) + ((e[4] + e[5]) + (e[6] + e[7])))
         + (((e[8] + e[9]) + (e[10] + e[11])) + ((e[12] + e[13]) + (e[14] + e[15])));
    // c[m] = packed (kv_even, kv_odd): kv = {0,1,2,3, 8,9,10,11, 16,..., 24,...}+4h
    unsigned int c[8];
#pragma unroll
    for (int m = 0; m < 8; m++) c[m] = pk2(e[2 * m], e[2 * m + 1]);
    // B-frag needs kv = s*16 + h*8 + j: exchange pair-halves across lane^32
    i32x2 r02 = plswap(c[0], c[2]);
    i32x2 r13 = plswap(c[1], c[3]);
    i32x2 r46 = plswap(c[4], c[6]);
    i32x2 r57 = plswap(c[5], c[7]);
    bf16x8 pf[2];
    u32x4 f0 = {(unsigned)r02[0], (unsigned)r13[0], (unsigned)r02[1], (unsigned)r13[1]};
    u32x4 f1 = {(unsigned)r46[0], (unsigned)r57[0], (unsigned)r46[1], (unsigned)r57[1]};
    __builtin_memcpy(&pf[0], &f0, 16);
    __builtin_memcpy(&pf[1], &f1, 16);

    // PV: O^T += V^T P  (A: row d=tt*32+l31, k(kv) = kvb + s*16 + h*8 + j)
    __builtin_amdgcn_s_setprio(1);
#pragma unroll
    for (int s = 0; s < 2; s++) {
#pragma unroll
      for (int tt = 0; tt < 2; tt++) {
        bf16x8 av = *(const bf16x8*)&Vcur[(tt * 32 + l31) * 64 + ((((kvb >> 3) + s * 2 + h) ^ rsw) * 8)];
        accO[tt] = __builtin_amdgcn_mfma_f32_32x32x16_bf16(av, pf[s], accO[tt], 0, 0, 0);
      }
    }
    __builtin_amdgcn_s_setprio(0);

    __syncthreads();  // next tile staged + all waves done with current buffers
  }

  // ---- epilogue: combine kv-halves (waves w and w+4 share q-strip) ----
  float* Red = (float*)LDS;  // K/V buffers dead after final barrier
  if (w >= 4) {
    const int base = (w - 4) * 2048;
#pragma unroll
    for (int tt = 0; tt < 2; tt++)
#pragma unroll
      for (int m = 0; m < 4; m++) {
        f32x4 v4 = {accO[tt][4 * m], accO[tt][4 * m + 1], accO[tt][4 * m + 2], accO[tt][4 * m + 3]};
        *(f32x4*)&Red[base + (tt * 4 + m) * 256 + lane * 4] = v4;  // lane-contiguous, conflict-free
      }
    Red[8192 + (w - 4) * 64 + lane] = psv;
  }
  __syncthreads();
  if (w < 4) {
#pragma unroll
    for (int tt = 0; tt < 2; tt++)
#pragma unroll
      for (int m = 0; m < 4; m++) {
        f32x4 v4 = *(const f32x4*)&Red[w * 2048 + (tt * 4 + m) * 256 + lane * 4];
        accO[tt][4 * m + 0] += v4[0];
        accO[tt][4 * m + 1] += v4[1];
        accO[tt][4 * m + 2] += v4[2];
        accO[tt][4 * m + 3] += v4[3];
      }
    psv += Red[8192 + w * 64 + lane];
    psv += __shfl_xor(psv, 32, 64);  // combine h-halves -> full l(q)
    const float linv = 1.0f / psv;
    const int srow = q0 + qs * 32 + l31;
    const int orow = g * 128 + (srow >> 4);
    const int cbase = (srow & 15) * 64;
#pragma unroll
    for (int tt = 0; tt < 2; tt++)
#pragma unroll
      for (int m = 0; m < 4; m++) {
        ushort4 o;
        o.x = f2b(accO[tt][4 * m + 0] * linv);
        o.y = f2b(accO[tt][4 * m + 1] * linv);
        o.z = f2b(accO[tt][4 * m + 2] * linv);
        o.w = f2b(accO[tt][4 * m + 3] * linv);
        *(ushort4*)&Oc[(size_t)orow * 1024 + cbase + tt * 32 + m * 8 + h * 4] = o;
      }
  }
}

extern "C" void kernel_launch(void* const* d_in, const int* in_sizes, int n_in,
                              void* d_out, int out_size, void* d_ws, size_t ws_size,
                              hipStream_t stream) {
  (void)in_sizes; (void)n_in; (void)out_size; (void)ws_size;
  const float* x    = (const float*)d_in[0];
  const float* ln_g = (const float*)d_in[1];
  const float* ln_b = (const float*)d_in[2];
  const float* W1   = (const float*)d_in[3];
  const float* b1   = (const float*)d_in[4];
  const float* W2   = (const float*)d_in[5];
  const float* b2   = (const float*)d_in[6];

  char* ws = (char*)d_ws;
  u16* xn   = (u16*)(ws);                       // 8 MB [0,8M)  (reused as Oc)
  u16* W1T  = (u16*)(ws + ((size_t)8 << 20));   // 6 MB
  u16* W2T  = (u16*)(ws + ((size_t)14 << 20));  // 2 MB
  u16* Qc   = (u16*)(ws + ((size_t)16 << 20));  // 8 MB
  u16* Kc   = (u16*)(ws + ((size_t)24 << 20));  // 8 MB
  u16* Vtmp = (u16*)(ws + ((size_t)32 << 20));  // 8 MB
  u16* Vt   = (u16*)(ws + ((size_t)40 << 20));  // 8 MB (total 48 MB)
  u16* Oc   = xn;

  pre_kernel<<<dim3(2048), dim3(256), 0, stream>>>(x, ln_g, ln_b, xn, W1, W1T, W2, W2T);
  gemm_bt<1, 128><<<dim3(768), dim3(256), 0, stream>>>(xn, W1T, b1, nullptr,
                                                       4096, 3072, 1024, 24, Qc, Kc, Vtmp);
  vtrans<<<dim3(32, 32), dim3(256), 0, stream>>>(Vtmp, Vt);
  attn_kernel<<<dim3(16, 32), dim3(512), 0, stream>>>(Qc, Kc, Vt, Oc);
  gemm_bt<0, 64><<<dim3(512), dim3(256), 0, stream>>>(Oc, W2T, b2, (float*)d_out,
                                                      4096, 1024, 1024, 8, nullptr, nullptr, nullptr);
}

// Round 10
// 185.536 us; speedup vs baseline: 1.0104x; 1.0104x over previous
//
#include <hip/hip_runtime.h>

typedef unsigned short u16;
typedef __bf16 bf16x8 __attribute__((ext_vector_type(8)));
typedef float f32x4 __attribute__((ext_vector_type(4)));
typedef float f32x16 __attribute__((ext_vector_type(16)));
typedef unsigned int u32x4 __attribute__((ext_vector_type(4)));
typedef int i32x2 __attribute__((ext_vector_type(2)));

// B=2, S=2048, E=1024, HID=1024, HEADS=16 -> M=4096 rows, 3N=3072, 32 (h,b) pairs
static constexpr float SCALE2 = 0.022097086912079608f * 1.4426950408889634f;  // qk scale * log2(e)

__device__ __forceinline__ u16 f2b(float f) {
  union { float f; unsigned int i; } v; v.f = f;
  unsigned int r = v.i + 0x7fffu + ((v.i >> 16) & 1u);  // RNE
  return (u16)(r >> 16);
}
// pack two f32 -> two bf16 in one u32 (HW cvt_pk if available)
__device__ __forceinline__ unsigned int pk2(float a, float b) {
#if __has_builtin(__builtin_amdgcn_cvt_pk_bf16_f32)
  auto v = __builtin_amdgcn_cvt_pk_bf16_f32(a, b);
  unsigned int u;
  __builtin_memcpy(&u, &v, 4);
  return u;
#else
  union { float f; unsigned int i; } x, y; x.f = a; y.f = b;
  return ((x.i + 0x8000u) >> 16) | ((y.i + 0x8000u) & 0xffff0000u);
#endif
}
// permlane32_swap: exchange lanes 0-31 of one reg with lanes 32-63 of another.
// returns {d, s}: d = [a_lo | b_lo], s = [a_hi | b_hi]  (lo = lanes 0-31 view)
__device__ __forceinline__ i32x2 plswap(unsigned int a, unsigned int b) {
#if __has_builtin(__builtin_amdgcn_permlane32_swap)
  return __builtin_amdgcn_permlane32_swap((int)a, (int)b, false, false);
#else
  int d = (int)a, s = (int)b;
  asm volatile("v_permlane32_swap_b32 %0, %1" : "+v"(d), "+v"(s));
  i32x2 r; r[0] = d; r[1] = s; return r;
#endif
}
__device__ __forceinline__ void async16(const u16* g, u16* l) {
  __builtin_amdgcn_global_load_lds((const __attribute__((address_space(1))) void*)g,
                                   (__attribute__((address_space(3))) void*)l,
                                   16, 0, 0);
}

// ---- fused pre-pass: LN wave-per-row (blocks 0..1023, 4 rows/block,
// no LDS, no barriers) + W1/W2 transpose+cast (1024..2047) ----
__global__ __launch_bounds__(256) void pre_kernel(const float* __restrict__ x,
                                                  const float* __restrict__ lg,
                                                  const float* __restrict__ lb,
                                                  u16* __restrict__ xn,
                                                  const float* __restrict__ W1,
                                                  u16* __restrict__ W1T,
                                                  const float* __restrict__ W2,
                                                  u16* __restrict__ W2T) {
  __shared__ __align__(16) u16 smem[64 * 72];
  const int bx = blockIdx.x;
  const int t = threadIdx.x;
  if (bx < 1024) {
    // -------- LayerNorm: wave w owns row bx*4 + w; pure shfl reduce --------
    const int w = t >> 6, lane = t & 63;
    const int row = bx * 4 + w;
    const float* xr = x + (size_t)row * 1024;
    float4 v[4];
    float s = 0.f, ss = 0.f;
#pragma unroll
    for (int k = 0; k < 4; k++) {
      v[k] = *(const float4*)(xr + k * 256 + lane * 4);
      s += v[k].x + v[k].y + v[k].z + v[k].w;
      ss += v[k].x * v[k].x + v[k].y * v[k].y + v[k].z * v[k].z + v[k].w * v[k].w;
    }
#pragma unroll
    for (int off = 32; off >= 1; off >>= 1) {
      s += __shfl_xor(s, off, 64);
      ss += __shfl_xor(ss, off, 64);
    }
    const float mu = s * (1.0f / 1024.0f);
    const float var = ss * (1.0f / 1024.0f) - mu * mu;
    const float inv = rsqrtf(var + 1e-5f);
#pragma unroll
    for (int k = 0; k < 4; k++) {
      float4 gg = *(const float4*)(lg + k * 256 + lane * 4);
      float4 bb = *(const float4*)(lb + k * 256 + lane * 4);
      ushort4 o;
      o.x = f2b((v[k].x - mu) * inv * gg.x + bb.x);
      o.y = f2b((v[k].y - mu) * inv * gg.y + bb.y);
      o.z = f2b((v[k].z - mu) * inv * gg.z + bb.z);
      o.w = f2b((v[k].w - mu) * inv * gg.w + bb.w);
      *(ushort4*)(xn + (size_t)row * 1024 + k * 256 + lane * 4) = o;
    }
    return;
  }
  // -------- weight transpose tile --------
  const float* in;
  u16* out;
  int C, c0, r0;
  if (bx < 1024 + 768) {
    const int idx = bx - 1024;
    C = 3072; in = W1; out = W1T;
    c0 = (idx % 48) * 64; r0 = (idx / 48) * 64;
  } else {
    const int idx = bx - 1792;
    C = 1024; in = W2; out = W2T;
    c0 = (idx % 16) * 64; r0 = (idx / 16) * 64;
  }
  const int row = t >> 2, cseg = t & 3;
  for (int it = 0; it < 4; it++) {
    float4 v = *(const float4*)&in[(size_t)(r0 + row) * C + c0 + it * 16 + cseg * 4];
    ushort4 o;
    o.x = f2b(v.x); o.y = f2b(v.y); o.z = f2b(v.z); o.w = f2b(v.w);
    *(ushort4*)&smem[row * 72 + it * 16 + cseg * 4] = o;
  }
  __syncthreads();
  const int orow = t >> 2, ch = t & 3;
  u16 vals[16];
  for (int j = 0; j < 16; j++) vals[j] = smem[(ch * 16 + j) * 72 + orow];
  u16* dp = out + (size_t)(c0 + orow) * 1024 + r0 + ch * 16;
  *(uint4*)&dp[0] = *(uint4*)&vals[0];
  *(uint4*)&dp[8] = *(uint4*)&vals[8];
}

// ------- GEMM (B^T input): C[M][N] = A[M][K] * Bt[N][K]^T + bias -------
// BK=64 (32 MFMAs per barrier-pair) + bijective XCD swizzle (1D grid,
// nwg%8==0).  LDS layout [rows][64] with chunk^(row&7) XOR swizzle (16-B
// chunks), consistent between staging (pre-swizzled global source) and
// fragment reads -> <=2-way conflicts.
// MT x 128 block tile, 4 waves (2x2), 16x16x32 MFMA.
// MODE 0: C = float* row-major.
// MODE 1 (MT=128 only): coalesced bf16 stores into Qc/Kc/Vtmp [g][2048][64];
//   Q values pre-scaled by SCALE2 (folded attention scale).
template <int MODE, int MT>
__global__ __launch_bounds__(256) void gemm_bt(const u16* __restrict__ A,
                                               const u16* __restrict__ Bt,
                                               const float* __restrict__ bias,
                                               float* __restrict__ C,
                                               int M, int N, int K, int nbx,
                                               u16* __restrict__ Qc,
                                               u16* __restrict__ Kc,
                                               u16* __restrict__ Vtmp) {
  __shared__ __align__(16) u16 SMEM[(MT + 128) * 64];
  u16* As = SMEM;            // [MT][64]
  u16* Bs = SMEM + MT * 64;  // [128][64]
  // XCD-aware bijective remap: consecutive blockIdx round-robin XCDs ->
  // give each XCD a contiguous run of tiles (A-panel L2 reuse).
  const int nwg = gridDim.x, cpx = nwg >> 3;
  const int l0 = blockIdx.x;
  const int l2 = (l0 & 7) * cpx + (l0 >> 3);
  const int bx = l2 % nbx, by = l2 / nbx;
  const int m0 = by * MT, n0 = bx * 128;
  const int t = threadIdx.x, w = t >> 6, lane = t & 63;
  const int q = lane >> 4, l16 = lane & 15;
  const int wm = (w >> 1) * (MT / 2), wn = (w & 1) * 64;
  constexpr int NI = MT / 32;

  // staging: each async16 covers 8 rows x 64 cols; lane (l>>3)=row, (l&7)=chunk.
  // LDS[r][c] = G[r][c ^ (r&7)]  (chunks of 8 u16)
  const int gchunk = (lane & 7) ^ ((lane >> 3) & 7);
  const u16* ap = A + (size_t)(m0 + w * 8 + (lane >> 3)) * K + gchunk * 8;
  const u16* bp = Bt + (size_t)(n0 + w * 8 + (lane >> 3)) * K + gchunk * 8;
  u16* lA = &As[w * 512];
  u16* lB = &Bs[w * 512];

  f32x4 acc[NI][4];
  const f32x4 zero = {0.f, 0.f, 0.f, 0.f};
  for (int i = 0; i < NI; i++)
    for (int j = 0; j < 4; j++) acc[i][j] = zero;

  for (int k0 = 0; k0 < K; k0 += 64) {
    for (int i = 0; i < MT / 32; i++)
      async16(ap + (size_t)(i * 32) * K, lA + i * 2048);
    for (int i = 0; i < 4; i++)
      async16(bp + (size_t)(i * 32) * K, lB + i * 2048);
    ap += 64; bp += 64;
    __syncthreads();
    for (int kk = 0; kk < 2; kk++) {
      bf16x8 af[NI], bfr[4];
      for (int i = 0; i < NI; i++) {
        const int r = wm + i * 16 + l16;
        af[i] = *(const bf16x8*)&As[r * 64 + (((kk * 4 + q) ^ (r & 7)) * 8)];
      }
      for (int j = 0; j < 4; j++) {
        const int r = wn + j * 16 + l16;
        bfr[j] = *(const bf16x8*)&Bs[r * 64 + (((kk * 4 + q) ^ (r & 7)) * 8)];
      }
      for (int i = 0; i < NI; i++)
        for (int j = 0; j < 4; j++)
          acc[i][j] = __builtin_amdgcn_mfma_f32_16x16x32_bf16(af[i], bfr[j], acc[i][j], 0, 0, 0);
    }
    __syncthreads();
  }

  if constexpr (MODE == 0) {
    for (int j = 0; j < 4; j++) {
      const int col = n0 + wn + j * 16 + l16;
      const float bv = bias[col];
      for (int i = 0; i < NI; i++) {
        const int rbase = m0 + wm + i * 16 + q * 4;
        for (int r = 0; r < 4; r++)
          C[(size_t)(rbase + r) * N + col] = acc[i][j][r] + bv;
      }
    }
  } else {
    // wave's 64-col segment: one type, fixed tcol.  seg = 64k -> typ = k%3, tcol = k/3.
    const int seg = n0 + wn;
    const int k64 = seg >> 6;
    const int tcol = k64 / 3;
    const int typ = k64 - tcol * 3;  // 0=Q,1=K,2=V
    u16* dst = (typ == 0) ? Qc : (typ == 1) ? Kc : Vtmp;
    const float qs = (typ == 0) ? SCALE2 : 1.0f;  // fold attention scale into Q
    const int gidx = m0 >> 7;
    u16* tw = &SMEM[w * 1280];  // [64 cols][20] u16, wave-private
    float bv[4];
    for (int j = 0; j < 4; j++) bv[j] = bias[seg + j * 16 + l16];
    __syncthreads();  // all waves done with As/Bs MFMA reads
    for (int i = 0; i < 4; i++) {
      for (int j = 0; j < 4; j++) {
        ushort4 pk;
        pk.x = f2b((acc[i][j][0] + bv[j]) * qs);
        pk.y = f2b((acc[i][j][1] + bv[j]) * qs);
        pk.z = f2b((acc[i][j][2] + bv[j]) * qs);
        pk.w = f2b((acc[i][j][3] + bv[j]) * qs);
        *(ushort4*)&tw[(j * 16 + l16) * 20 + q * 4] = pk;  // col-major, pad 20
      }
      const int r2 = lane >> 2;
      const int quarter = lane & 3;
      u16 vals[16];
      for (int c = 0; c < 16; c++)
        vals[c] = tw[(quarter * 16 + c) * 20 + r2];
      const int lr = wm + i * 16 + r2;
      const int s = (lr << 4) + tcol;
      u16* dp = dst + ((size_t)gidx * 2048 + s) * 64 + quarter * 16;
      *(uint4*)&dp[0] = *(uint4*)&vals[0];
      *(uint4*)&dp[8] = *(uint4*)&vals[8];
    }
  }
}

// ------- vtrans: Vtmp[g][2048][64] -> Vt[g][64][2048], 64x64 LDS tiles -------
__global__ __launch_bounds__(256) void vtrans(const u16* __restrict__ Vtmp,
                                              u16* __restrict__ Vt) {
  __shared__ __align__(16) u16 tile[64 * 64];  // XOR-swizzled chunks
  const int g = blockIdx.y, s0 = blockIdx.x * 64;
  const int t = threadIdx.x;
  const int row = t >> 3, ch = t & 7;
  for (int p = 0; p < 2; p++) {
    const int r = p * 32 + row;
    uint4 v = *(const uint4*)&Vtmp[((size_t)g * 2048 + s0 + r) * 64 + ch * 8];
    *(uint4*)&tile[r * 64 + ((ch ^ (r & 7)) * 8)] = v;
  }
  __syncthreads();
  const int d = t >> 2, scn = t & 3;
  u16 vals[16];
  for (int j2 = 0; j2 < 16; j2++) {
    const int s = scn * 16 + j2;
    vals[j2] = tile[s * 64 + (((d >> 3) ^ (s & 7)) * 8) + (d & 7)];
  }
  u16* dp = Vt + ((size_t)g * 64 + d) * 2048 + s0 + scn * 16;
  *(uint4*)&dp[0] = *(uint4*)&vals[0];
  *(uint4*)&dp[8] = *(uint4*)&vals[8];
}

// ------- flash attention: 1 block per (g, q-tile 128), 8 waves -------
// R9: R3 structure + inner-loop VALU trim: #pragma unroll 2 makes the
// double-buffer select compile-time static (no per-iter cndmask/select),
// and staging addresses are pointer-bumped (+= const) instead of
// recomputed from it.  Math byte-identical to R3 (absmax 2.4e-4).
// 8 waves = 2 kv-halves x 4 q-strips(32); 32x32 MFMA; in-register
// P redistribution (cvt_pk + permlane32_swap); no Ps LDS; 64-kv sub-tiles,
// double-buffered K/V via global_load_lds.
// Swizzles (c = 16-B chunk): Ks[s'][c]=K[s'][c^(s'&7)], Vs[d][c]=V^T[d][c^(d&7)].
__global__ __launch_bounds__(512) void attn_kernel(const u16* __restrict__ Qc,
                                                   const u16* __restrict__ Kc,
                                                   const u16* __restrict__ Vt,
                                                   u16* __restrict__ Oc) {
  __shared__ __align__(16) u16 LDS[25600];  // 50 KB: K dbuf 16K | V dbuf 16K | epilogue reuse
  u16* K0 = LDS;           // [64][64] buf 0
  u16* K1 = LDS + 4096;    // buf 1
  u16* V0 = LDS + 8192;    // V^T slice [64][64] buf 0
  u16* V1 = LDS + 12288;   // buf 1
  const int g = blockIdx.y;
  const int q0 = blockIdx.x * 128;
  const int t = threadIdx.x, w = t >> 6, lane = t & 63;
  const int l31 = lane & 31, h = lane >> 5;
  const int qs = w & 3;           // q-strip (32 rows)
  const int kvb = (w >> 2) * 32;  // kv half base

  const u16* Qg = Qc + (size_t)g * 2048 * 64;
  const u16* Kg = Kc + (size_t)g * 2048 * 64;
  const u16* Vg = Vt + (size_t)g * 64 * 2048;

  // Q B-frags (pre-scaled by SCALE2): lane: col q=l31, k(d) = s*16 + h*8 + j
  bf16x8 aq[4];
#pragma unroll
  for (int s = 0; s < 4; s++)
    aq[s] = *(const bf16x8*)&Qg[(size_t)(q0 + qs * 32 + l31) * 64 + s * 16 + h * 8];

  f32x16 accO[2];  // O^T partial (this wave's kv half): d = tt*32+(r&3)+8*(r>>2)+4h, q=l31
#pragma unroll
  for (int tt = 0; tt < 2; tt++)
#pragma unroll
    for (int r = 0; r < 16; r++) accO[tt][r] = 0.f;
  float psv = 0.f;  // partial l-sum (this lane's 16 kv rows, q=l31)

  // staging: wave w covers rows w*8..w*8+7 of each 64-row tile (1 K + 1 V load)
  const int ch = (lane & 7) ^ ((lane >> 3) & 7);
  const u16* kp = Kg + (size_t)(w * 8 + (lane >> 3)) * 64 + ch * 8;
  const u16* vp = Vg + (size_t)(w * 8 + (lane >> 3)) * 2048 + ch * 8;
  u16* lK0 = K0 + w * 512;
  u16* lK1 = K1 + w * 512;
  u16* lV0 = V0 + w * 512;
  u16* lV1 = V1 + w * 512;

  const int rsw = l31 & 7;  // row-based chunk swizzle for A-frag reads

  // prologue: stage tile 0 into buf 0
  async16(kp, lK0);
  async16(vp, lV0);
  __syncthreads();

  // prefetch cursors (pointer-bump: +4096 elems = next 64-kv K tile, +64 = next V slice)
  const u16* kpn = kp + 4096;
  const u16* vpn = vp + 64;

#pragma unroll 2
  for (int it = 0; it < 32; it++) {
    const int cur = it & 1;  // static under unroll-2
    const u16* Kcur = cur ? K1 : K0;
    const u16* Vcur = cur ? V1 : V0;
    // prefetch next tile into the other buffer (overlaps with compute below)
    if (it < 31) {
      async16(kpn, cur ? lK0 : lK1);
      async16(vpn, cur ? lV0 : lV1);
      kpn += 4096;
      vpn += 64;
    }

    // S^T[32kv][32q] = K Q^T  (A: row kv=kvb+l31, k = s*16+h*8+j)
    f32x16 sa;
#pragma unroll
    for (int r = 0; r < 16; r++) sa[r] = 0.f;
    __builtin_amdgcn_s_setprio(1);
#pragma unroll
    for (int s = 0; s < 4; s++) {
      bf16x8 ak = *(const bf16x8*)&Kcur[(kvb + l31) * 64 + (((s * 2 + h) ^ rsw) * 8)];
      sa = __builtin_amdgcn_mfma_f32_32x32x16_bf16(ak, aq[s], sa, 0, 0, 0);
    }
    __builtin_amdgcn_s_setprio(0);

    // softmax: exp2, l-sum partial, pack to bf16 pairs, permlane32 redistribution
    float e[16];
#pragma unroll
    for (int r = 0; r < 16; r++) e[r] = __builtin_amdgcn_exp2f(sa[r]);
    psv += (((e[0] + e[1]) + (e[2] + e[3])) + ((e[4] + e[5]) + (e[6] + e[7])))
         + (((e[8] + e[9]) + (e[10] + e[11])) + ((e[12] + e[13]) + (e[14] + e[15])));
    // c[m] = packed (kv_even, kv_odd): kv = {0,1,2,3, 8,9,10,11, 16,..., 24,...}+4h
    unsigned int c[8];
#pragma unroll
    for (int m = 0; m < 8; m++) c[m] = pk2(e[2 * m], e[2 * m + 1]);
    // B-frag needs kv = s*16 + h*8 + j: exchange pair-halves across lane^32
    i32x2 r02 = plswap(c[0], c[2]);
    i32x2 r13 = plswap(c[1], c[3]);
    i32x2 r46 = plswap(c[4], c[6]);
    i32x2 r57 = plswap(c[5], c[7]);
    bf16x8 pf[2];
    u32x4 f0 = {(unsigned)r02[0], (unsigned)r13[0], (unsigned)r02[1], (unsigned)r13[1]};
    u32x4 f1 = {(unsigned)r46[0], (unsigned)r57[0], (unsigned)r46[1], (unsigned)r57[1]};
    __builtin_memcpy(&pf[0], &f0, 16);
    __builtin_memcpy(&pf[1], &f1, 16);

    // PV: O^T += V^T P  (A: row d=tt*32+l31, k(kv) = kvb + s*16 + h*8 + j)
    __builtin_amdgcn_s_setprio(1);
#pragma unroll
    for (int s = 0; s < 2; s++) {
#pragma unroll
      for (int tt = 0; tt < 2; tt++) {
        bf16x8 av = *(const bf16x8*)&Vcur[(tt * 32 + l31) * 64 + ((((kvb >> 3) + s * 2 + h) ^ rsw) * 8)];
        accO[tt] = __builtin_amdgcn_mfma_f32_32x32x16_bf16(av, pf[s], accO[tt], 0, 0, 0);
      }
    }
    __builtin_amdgcn_s_setprio(0);

    __syncthreads();  // next tile staged + all waves done with current buffers
  }

  // ---- epilogue: combine kv-halves (waves w and w+4 share q-strip) ----
  float* Red = (float*)LDS;  // K/V buffers dead after final barrier
  if (w >= 4) {
    const int base = (w - 4) * 2048;
#pragma unroll
    for (int tt = 0; tt < 2; tt++)
#pragma unroll
      for (int m = 0; m < 4; m++) {
        f32x4 v4 = {accO[tt][4 * m], accO[tt][4 * m + 1], accO[tt][4 * m + 2], accO[tt][4 * m + 3]};
        *(f32x4*)&Red[base + (tt * 4 + m) * 256 + lane * 4] = v4;  // lane-contiguous, conflict-free
      }
    Red[8192 + (w - 4) * 64 + lane] = psv;
  }
  __syncthreads();
  if (w < 4) {
#pragma unroll
    for (int tt = 0; tt < 2; tt++)
#pragma unroll
      for (int m = 0; m < 4; m++) {
        f32x4 v4 = *(const f32x4*)&Red[w * 2048 + (tt * 4 + m) * 256 + lane * 4];
        accO[tt][4 * m + 0] += v4[0];
        accO[tt][4 * m + 1] += v4[1];
        accO[tt][4 * m + 2] += v4[2];
        accO[tt][4 * m + 3] += v4[3];
      }
    psv += Red[8192 + w * 64 + lane];
    psv += __shfl_xor(psv, 32, 64);  // combine h-halves -> full l(q)
    const float linv = 1.0f / psv;
    const int srow = q0 + qs * 32 + l31;
    const int orow = g * 128 + (srow >> 4);
    const int cbase = (srow & 15) * 64;
#pragma unroll
    for (int tt = 0; tt < 2; tt++)
#pragma unroll
      for (int m = 0; m < 4; m++) {
        ushort4 o;
        o.x = f2b(accO[tt][4 * m + 0] * linv);
        o.y = f2b(accO[tt][4 * m + 1] * linv);
        o.z = f2b(accO[tt][4 * m + 2] * linv);
        o.w = f2b(accO[tt][4 * m + 3] * linv);
        *(ushort4*)&Oc[(size_t)orow * 1024 + cbase + tt * 32 + m * 8 + h * 4] = o;
      }
  }
}

extern "C" void kernel_launch(void* const* d_in, const int* in_sizes, int n_in,
                              void* d_out, int out_size, void* d_ws, size_t ws_size,
                              hipStream_t stream) {
  (void)in_sizes; (void)n_in; (void)out_size; (void)ws_size;
  const float* x    = (const float*)d_in[0];
  const float* ln_g = (const float*)d_in[1];
  const float* ln_b = (const float*)d_in[2];
  const float* W1   = (const float*)d_in[3];
  const float* b1   = (const float*)d_in[4];
  const float* W2   = (const float*)d_in[5];
  const float* b2   = (const float*)d_in[6];

  char* ws = (char*)d_ws;
  u16* xn   = (u16*)(ws);                       // 8 MB [0,8M)  (reused as Oc)
  u16* W1T  = (u16*)(ws + ((size_t)8 << 20));   // 6 MB
  u16* W2T  = (u16*)(ws + ((size_t)14 << 20));  // 2 MB
  u16* Qc   = (u16*)(ws + ((size_t)16 << 20));  // 8 MB
  u16* Kc   = (u16*)(ws + ((size_t)24 << 20));  // 8 MB
  u16* Vtmp = (u16*)(ws + ((size_t)32 << 20));  // 8 MB
  u16* Vt   = (u16*)(ws + ((size_t)40 << 20));  // 8 MB (total 48 MB)
  u16* Oc   = xn;

  pre_kernel<<<dim3(2048), dim3(256), 0, stream>>>(x, ln_g, ln_b, xn, W1, W1T, W2, W2T);
  gemm_bt<1, 128><<<dim3(768), dim3(256), 0, stream>>>(xn, W1T, b1, nullptr,
                                                       4096, 3072, 1024, 24, Qc, Kc, Vtmp);
  vtrans<<<dim3(32, 32), dim3(256), 0, stream>>>(Vtmp, Vt);
  attn_kernel<<<dim3(16, 32), dim3(512), 0, stream>>>(Qc, Kc, Vt, Oc);
  gemm_bt<0, 64><<<dim3(512), dim3(256), 0, stream>>>(Oc, W2T, b2, (float*)d_out,
                                                      4096, 1024, 1024, 8, nullptr, nullptr, nullptr);
}